// Round 6
// baseline (282.215 us; speedup 1.0000x reference)
//
#include <hip/hip_runtime.h>
#include <hip/hip_bf16.h>
#include <cmath>

// ---------------------------------------------------------------------------
// Causal single-head self-attention, B=4 T=2048 C=1024, fp32 in/out,
// bf16 MFMA internally.
// R1: LDS xor-swizzle (conflicts -> 0), causal tile skip + K-cap.
// R2: fused QKV projection (N=3072, V transposed in epilogue), XCD swizzle.
// R3: NB=2 dbuf -> NEUTRAL. R4: NW=8 -> NEUTRAL (lower LDS-BW ceiling).
// R5 model: K-loop is LDS-read-BW-bound (128 B/cyc/CU, staging writes on the
//   DMA path are free). acc4x4/64x64-per-wave = 32.8 FLOP/B -> ~31% MfmaUtil
//   ceiling; QKV measures 33% (at ceiling, 844 TF). S/PV/Out ran at half that
//   because 2 blocks/CU can't cover the barrier drain (m114: need >=3).
// R5 fix: 64x64-tile SINGLE-WAVE blocks (16KB LDS, same 32.8 FLOP/B) ->
//   2048/528-block grids = 8 independent blocks/CU. Causal granularity 64.
// ---------------------------------------------------------------------------

typedef __attribute__((ext_vector_type(8))) __bf16 bf16x8;
typedef __attribute__((ext_vector_type(8))) short short8;
typedef __attribute__((ext_vector_type(4))) float f32x4;

__device__ __forceinline__ unsigned short f2bf(float f) {
  union { float f; unsigned u; } v; v.f = f;
  unsigned u = v.u;
  u += ((u >> 16) & 1u) + 0x7fffu;   // round-to-nearest-even
  return (unsigned short)(u >> 16);
}
__device__ __forceinline__ float bf2f(unsigned short h) {
  union { unsigned u; float f; } v; v.u = ((unsigned)h) << 16;
  return v.f;
}

#define GLDS(gp, sp)                                                           \
  __builtin_amdgcn_global_load_lds(                                            \
      (const __attribute__((address_space(1))) void*)(gp),                     \
      (__attribute__((address_space(3))) void*)(sp), 16, 0, 0)

// --------- prep: z<4 transpose+cast weights, z>=4 cast X fp32->bf16 --------
__global__ void prep(const float* __restrict__ X,
                     const float* __restrict__ w0, const float* __restrict__ w1,
                     const float* __restrict__ w2, const float* __restrict__ w3,
                     unsigned short* __restrict__ Xb,
                     unsigned short* __restrict__ wcat,   // [3C][C]
                     unsigned short* __restrict__ wot,    // [C][C]
                     int n) {
  if (blockIdx.z < 4) {
    const float* src = blockIdx.z == 0 ? w0 : blockIdx.z == 1 ? w1
                       : blockIdx.z == 2 ? w2 : w3;
    unsigned short* dst =
        blockIdx.z < 3 ? wcat + (size_t)blockIdx.z * n * n : wot;
    __shared__ float tile[32][33];
    int bx = blockIdx.x * 32, by = blockIdx.y * 32;
    int tx = threadIdx.x, ty = threadIdx.y;
#pragma unroll
    for (int i = 0; i < 32; i += 8)
      tile[ty + i][tx] = src[(size_t)(by + ty + i) * n + bx + tx];
    __syncthreads();
#pragma unroll
    for (int i = 0; i < 32; i += 8)
      dst[(size_t)(bx + ty + i) * n + by + tx] = f2bf(tile[tx][ty + i]);
  } else {
    const int bid = (blockIdx.z - 4) * 1024 + blockIdx.y * 32 + blockIdx.x;
    const int t = threadIdx.y * 32 + threadIdx.x;
    const int i = (bid * 256 + t) * 4;
    float4 f = *(const float4*)(X + i);
    ushort4 o = make_ushort4(f2bf(f.x), f2bf(f.y), f2bf(f.z), f2bf(f.w));
    *(ushort4*)(Xb + i) = o;
  }
}

// ----------------------- QKV GEMM (128x128, 4 waves) -----------------------
// C[m][n] = sum_k A[m][k] * Bt[n][k]; N=3072 fused; XCD swizzle via gx.
// Epilogue: Q (col<1024) | K (+8M elems) | V transposed at +16M as Vt[b][c][t].
__global__ __launch_bounds__(256, 2)
void gemm_qkv(const unsigned short* __restrict__ A, int lda,
              const unsigned short* __restrict__ B, int ldb,
              unsigned short* __restrict__ Cp, int K, int gx) {
  const int id = blockIdx.x;
  const int gs = gx * 8;
  const int g = id / gs, r = id - g * gs;
  const int bx = r >> 3;
  const int by = g * 8 + (r & 7);
  const int m0 = by * 128;
  const int n0 = bx * 128;

  const int tid  = threadIdx.x;
  const int lane = tid & 63;
  const int w    = tid >> 6;
  const int wm   = (w >> 1) * 64;
  const int wn   = (w & 1) * 64;
  const int quad = lane >> 4;
  const int l16  = lane & 15;

  __shared__ unsigned short As[8192];
  __shared__ unsigned short Bs[8192];

  f32x4 acc[4][4];
#pragma unroll
  for (int i = 0; i < 4; ++i)
#pragma unroll
    for (int j = 0; j < 4; ++j)
      acc[i][j] = (f32x4){0.f, 0.f, 0.f, 0.f};

  const int srow = tid >> 3;
  const int scol = ((tid & 7) ^ (srow & 7)) * 8;
  const unsigned short* gA = A + (long long)(m0 + srow) * lda + scol;
  const unsigned short* gB = B + (long long)(n0 + srow) * ldb + scol;
  const int rsw = l16 & 7;

  for (int kt = 0; kt < K; kt += 64) {
    __syncthreads();
#pragma unroll
    for (int r2 = 0; r2 < 4; ++r2) {
      GLDS(gA + (long long)(r2 * 32) * lda + kt, As + r2 * 2048 + tid * 8);
      GLDS(gB + (long long)(r2 * 32) * ldb + kt, Bs + r2 * 2048 + tid * 8);
    }
    __syncthreads();
#pragma unroll
    for (int ks = 0; ks < 2; ++ks) {
      bf16x8 af[4], bfr[4];
#pragma unroll
      for (int i = 0; i < 4; ++i)
        af[i] = *(const bf16x8*)(As + (wm + i * 16 + l16) * 64 +
                                 ((ks * 4 + quad) ^ rsw) * 8);
#pragma unroll
      for (int j = 0; j < 4; ++j)
        bfr[j] = *(const bf16x8*)(Bs + (wn + j * 16 + l16) * 64 +
                                  ((ks * 4 + quad) ^ rsw) * 8);
#pragma unroll
      for (int i = 0; i < 4; ++i)
#pragma unroll
        for (int j = 0; j < 4; ++j)
          acc[i][j] = __builtin_amdgcn_mfma_f32_16x16x32_bf16(af[i], bfr[j],
                                                              acc[i][j], 0, 0, 0);
    }
  }

  // C/D layout (m89/m91 verified): col = lane&15, row = quad*4 + reg
#pragma unroll
  for (int i = 0; i < 4; ++i) {
#pragma unroll
    for (int j = 0; j < 4; ++j) {
      const int row = m0 + wm + i * 16 + quad * 4;
      const int col = n0 + wn + j * 16 + l16;
      if (col >= 2048) {  // V, stored transposed: Vt[b][c][t]
        const int b = row >> 11, t = row & 2047, cv = col - 2048;
        ushort4 o = make_ushort4(f2bf(acc[i][j][0]), f2bf(acc[i][j][1]),
                                 f2bf(acc[i][j][2]), f2bf(acc[i][j][3]));
        *(ushort4*)(Cp + 16777216LL + ((long long)(b * 1024 + cv)) * 2048 + t) = o;
      } else {  // Q (col<1024) or K (col in [1024,2048))
        unsigned short* dst = Cp + (col >= 1024 ? 8388608LL - 1024 : 0);
#pragma unroll
        for (int r2 = 0; r2 < 4; ++r2)
          dst[(long long)(row + r2) * 1024 + col] = f2bf(acc[i][j][r2]);
      }
    }
  }
}

// ------------------- small GEMM: 64x64 tile, ONE wave/block ----------------
// Same 32.8 FLOP/LDS-read-byte as the 4-wave kernel, but 16KB LDS -> 8+
// independent blocks/CU on 2048-block grids (barrier phases decorrelated).
// tri : blockIdx.x = lower-triangular 64-tile index (S GEMM).
// kcap: Keff = m0+64 (causal PV truncation), heavy rows dispatched first.
template <typename OutT>
__global__ __launch_bounds__(64, 2)
void gemm64(const unsigned short* __restrict__ A, int lda, long long sA,
            const unsigned short* __restrict__ B, int ldb, long long sB,
            OutT* __restrict__ Cp, int ldc, long long sC,
            int K, float alpha, int tri, int kcap) {
  A  += (long long)blockIdx.z * sA;
  B  += (long long)blockIdx.z * sB;
  Cp += (long long)blockIdx.z * sC;

  int by, bx;
  if (tri) {
    const int idx = blockIdx.x;
    by = (int)((sqrtf(8.f * idx + 1.f) - 1.f) * 0.5f);
    while (by * (by + 1) / 2 > idx) --by;
    while ((by + 1) * (by + 2) / 2 <= idx) ++by;
    bx = idx - by * (by + 1) / 2;
  } else {
    by = blockIdx.y;
    bx = blockIdx.x;
    if (kcap) by = gridDim.y - 1 - by;  // heavy rows first
  }
  const int m0 = by * 64;
  const int n0 = bx * 64;
  const int Keff = kcap ? min(K, m0 + 64) : K;

  const int lane = threadIdx.x;
  const int quad = lane >> 4;
  const int l16  = lane & 15;
  const int rsw  = l16 & 7;

  __shared__ unsigned short As[4096];
  __shared__ unsigned short Bs[4096];

  f32x4 acc[4][4];
#pragma unroll
  for (int i = 0; i < 4; ++i)
#pragma unroll
    for (int j = 0; j < 4; ++j)
      acc[i][j] = (f32x4){0.f, 0.f, 0.f, 0.f};

  // staging: 64 thr x 16B = 1KB/round = 8 rows x 64 cols; 8 rounds/operand.
  const int srow = lane >> 3;
  const int scol = ((lane & 7) ^ (srow & 7)) * 8;
  const unsigned short* gA = A + (long long)(m0 + srow) * lda + scol;
  const unsigned short* gB = B + (long long)(n0 + srow) * ldb + scol;

  for (int kt = 0; kt < Keff; kt += 64) {
    __syncthreads();
#pragma unroll
    for (int r = 0; r < 8; ++r) {
      GLDS(gA + (long long)(r * 8) * lda + kt, As + r * 512 + lane * 8);
      GLDS(gB + (long long)(r * 8) * ldb + kt, Bs + r * 512 + lane * 8);
    }
    __syncthreads();
#pragma unroll
    for (int ks = 0; ks < 2; ++ks) {
      bf16x8 af[4], bfr[4];
#pragma unroll
      for (int i = 0; i < 4; ++i)
        af[i] = *(const bf16x8*)(As + (i * 16 + l16) * 64 +
                                 ((ks * 4 + quad) ^ rsw) * 8);
#pragma unroll
      for (int j = 0; j < 4; ++j)
        bfr[j] = *(const bf16x8*)(Bs + (j * 16 + l16) * 64 +
                                  ((ks * 4 + quad) ^ rsw) * 8);
#pragma unroll
      for (int i = 0; i < 4; ++i)
#pragma unroll
        for (int j = 0; j < 4; ++j)
          acc[i][j] = __builtin_amdgcn_mfma_f32_16x16x32_bf16(af[i], bfr[j],
                                                              acc[i][j], 0, 0, 0);
    }
  }

#pragma unroll
  for (int i = 0; i < 4; ++i) {
#pragma unroll
    for (int j = 0; j < 4; ++j) {
      const int row = m0 + i * 16 + quad * 4;
      const int col = n0 + j * 16 + l16;
#pragma unroll
      for (int r = 0; r < 4; ++r) {
        float v = acc[i][j][r] * alpha;
        if constexpr (sizeof(OutT) == 2)
          Cp[(long long)(row + r) * ldc + col] = (OutT)f2bf(v);
        else
          Cp[(long long)(row + r) * ldc + col] = v;
      }
    }
  }
}

// ------------------------- causal softmax (in place) -----------------------
// limit now 64-granular: writes exactly cols [0, rnd64(t+1)) per row, which
// is exactly what the kcap-64 PV GEMM reads.
__global__ __launch_bounds__(256)
void softmax_causal(unsigned short* __restrict__ S, int T) {
  const long long row = blockIdx.x;
  const int t = (int)(row & (long long)(T - 1));
  const int limit = ((t >> 6) + 1) << 6;
  unsigned short* p = S + row * T;
  const int tid  = threadIdx.x;
  const int base = tid * 8;
  const bool active = base < limit;

  short8 raw = {};
  if (active) raw = *(const short8*)(p + base);
  float x[8];
  float mx = -1e30f;
#pragma unroll
  for (int j = 0; j < 8; ++j) {
    bool valid = active && (base + j) <= t;
    x[j] = valid ? bf2f((unsigned short)raw[j]) : -1e30f;
    mx = fmaxf(mx, x[j]);
  }
#pragma unroll
  for (int off = 32; off > 0; off >>= 1) mx = fmaxf(mx, __shfl_xor(mx, off));
  __shared__ float red[8];
  const int wv = tid >> 6;
  if ((tid & 63) == 0) red[wv] = mx;
  __syncthreads();
  mx = fmaxf(fmaxf(red[0], red[1]), fmaxf(red[2], red[3]));

  float sum = 0.f;
#pragma unroll
  for (int j = 0; j < 8; ++j) {
    bool valid = active && (base + j) <= t;
    x[j] = valid ? __expf(x[j] - mx) : 0.f;
    sum += x[j];
  }
#pragma unroll
  for (int off = 32; off > 0; off >>= 1) sum += __shfl_xor(sum, off);
  if ((tid & 63) == 0) red[4 + wv] = sum;
  __syncthreads();
  sum = red[4] + red[5] + red[6] + red[7];
  const float inv = 1.f / sum;

  if (active) {
    unsigned short out[8];
#pragma unroll
    for (int j = 0; j < 8; ++j) out[j] = f2bf(x[j] * inv);
    *(short8*)(p + base) = *(const short8*)out;
  }
}

// ---------------------------------------------------------------------------
extern "C" void kernel_launch(void* const* d_in, const int* in_sizes, int n_in,
                              void* d_out, int out_size, void* d_ws,
                              size_t ws_size, hipStream_t stream) {
  (void)in_sizes; (void)n_in; (void)out_size; (void)ws_size;
  const int Bb = 4, T = 2048, C = 1024;
  const int M = Bb * T;  // 8192

  const float* X  = (const float*)d_in[0];
  const float* Wq = (const float*)d_in[1];
  const float* Wk = (const float*)d_in[2];
  const float* Wv = (const float*)d_in[3];
  const float* Wo = (const float*)d_in[4];
  float* Out = (float*)d_out;

  char* w = (char*)d_ws;
  unsigned short* Xb   = (unsigned short*)w; w += (size_t)M * C * 2;      // 16MB
  unsigned short* Wcat = (unsigned short*)w; w += (size_t)3 * C * C * 2;  // 6MB
  unsigned short* Wot  = (unsigned short*)w; w += (size_t)C * C * 2;      // 2MB
  unsigned short* Q    = (unsigned short*)w; w += (size_t)M * C * 2;      // 16MB
  unsigned short* Kb   = (unsigned short*)w; w += (size_t)M * C * 2;      // 16MB (Q+8M)
  unsigned short* Vt   = (unsigned short*)w; w += (size_t)M * C * 2;      // 16MB (Q+16M)
  unsigned short* O    = Xb;                     // Xb dead after QKV GEMM
  unsigned short* S    = (unsigned short*)d_out; // 32MB, dead before final GEMM

  // prep: weights transpose+cast (z 0..3) + X cast (z 4..11)
  prep<<<dim3(32, 32, 12), dim3(32, 8), 0, stream>>>(X, Wq, Wk, Wv, Wo, Xb,
                                                     Wcat, Wot, C);

  // fused QKV: [8192 x 3072] = Xb @ Wcat^T-layout; 1536 blocks, 4-wave
  gemm_qkv<<<dim3((3 * C / 128) * (M / 128)), dim3(256), 0, stream>>>(
      Xb, C, Wcat, C, Q, C, /*gx=*/3 * C / 128);

  // S[b] = Q[b] @ K[b]^T / 32 — lower-tri 64-tiles: 528 x 4 = 2112 blocks
  const int ntri = (T / 64) * (T / 64 + 1) / 2;
  gemm64<unsigned short><<<dim3(ntri, 1, Bb), dim3(64), 0, stream>>>(
      Q, C, (long long)T * C, Kb, C, (long long)T * C,
      S, T, (long long)T * T, C, 0.03125f, 1, 0);

  // causal softmax (64-granular row truncation)
  softmax_causal<<<M, 256, 0, stream>>>(S, T);

  // O[b] = P[b] @ V[b], Keff = m0+64, heavy rows first: 16x32x4 = 2048 blocks
  gemm64<unsigned short><<<dim3(C / 64, T / 64, Bb), dim3(64), 0, stream>>>(
      S, T, (long long)T * T, Vt, T, (long long)C * T,
      O, C, (long long)T * C, T, 1.f, 0, 1);

  // Out = O @ Wo (fp32 epilogue): 16x128 = 2048 blocks
  gemm64<float><<<dim3(C / 64, M / 64, 1), dim3(64), 0, stream>>>(
      O, C, 0, Wot, C, 0, Out, C, 0, C, 1.f, 0, 0);
}

// Round 8
// 267.795 us; speedup vs baseline: 1.0538x; 1.0538x over previous
//
#include <hip/hip_runtime.h>
#include <hip/hip_bf16.h>
#include <cmath>

// ---------------------------------------------------------------------------
// Causal single-head self-attention, B=4 T=2048 C=1024, fp32 in/out,
// bf16 MFMA internally.
// R1: LDS xor-swizzle (conflicts -> 0), causal tile skip + K-cap.
// R2: fused QKV projection (N=3072, V transposed in epilogue), XCD swizzle.
// R3 dbuf / R4 8-wave / R6 1-wave: NEUTRAL -> small GEMMs critical-path bound.
// R7: Wo folded into V projection (out = P@(X@(Wv@Wo))) — FAILED: WvoT GEMM
//     used Wv^T instead of Wv (absmax 5.0), and carve assumed 90MB ws.
// R8: fix — Wv enters the WvoT GEMM as plain cast (no transpose); ws carve
//     back to proven 70MB (Wvb/Wot staged in d_out before S overwrites it;
//     PV writes fp32 to OutTmp over dead Q+Kb; d2d async copy to d_out).
// ---------------------------------------------------------------------------

typedef __attribute__((ext_vector_type(8))) __bf16 bf16x8;
typedef __attribute__((ext_vector_type(8))) short short8;
typedef __attribute__((ext_vector_type(4))) float f32x4;

__device__ __forceinline__ unsigned short f2bf(float f) {
  union { float f; unsigned u; } v; v.f = f;
  unsigned u = v.u;
  u += ((u >> 16) & 1u) + 0x7fffu;   // round-to-nearest-even
  return (unsigned short)(u >> 16);
}
__device__ __forceinline__ float bf2f(unsigned short h) {
  union { unsigned u; float f; } v; v.u = ((unsigned)h) << 16;
  return v.f;
}

#define GLDS(gp, sp)                                                           \
  __builtin_amdgcn_global_load_lds(                                            \
      (const __attribute__((address_space(1))) void*)(gp),                     \
      (__attribute__((address_space(3))) void*)(sp), 16, 0, 0)

// ------------------------------- prep --------------------------------------
// z=0: Wq -> Wcat[0] (transpose+cast)   z=1: Wk -> Wcat[1] (transpose+cast)
// z=2: Wv -> Wvb     (CAST ONLY — must enter WvoT GEMM un-transposed!)
// z=3: Wo -> Wot     (transpose+cast)   z>=4: X -> Xb (cast)
__global__ void prep(const float* __restrict__ X,
                     const float* __restrict__ w0, const float* __restrict__ w1,
                     const float* __restrict__ w2, const float* __restrict__ w3,
                     unsigned short* __restrict__ Xb,
                     unsigned short* __restrict__ wcat,   // [2C][C] used
                     unsigned short* __restrict__ wvb,    // [C][C] plain cast
                     unsigned short* __restrict__ wot,    // [C][C] transposed
                     int n) {
  if (blockIdx.z == 2) {  // plain cast Wv
    int bx = blockIdx.x * 32, by = blockIdx.y * 32;
    int tx = threadIdx.x, ty = threadIdx.y;
#pragma unroll
    for (int i = 0; i < 32; i += 8) {
      size_t idx = (size_t)(by + ty + i) * n + bx + tx;
      wvb[idx] = f2bf(w2[idx]);
    }
  } else if (blockIdx.z < 4) {
    const float* src = blockIdx.z == 0 ? w0 : blockIdx.z == 1 ? w1 : w3;
    unsigned short* dst = blockIdx.z == 0 ? wcat
                          : blockIdx.z == 1 ? wcat + (size_t)n * n : wot;
    __shared__ float tile[32][33];
    int bx = blockIdx.x * 32, by = blockIdx.y * 32;
    int tx = threadIdx.x, ty = threadIdx.y;
#pragma unroll
    for (int i = 0; i < 32; i += 8)
      tile[ty + i][tx] = src[(size_t)(by + ty + i) * n + bx + tx];
    __syncthreads();
#pragma unroll
    for (int i = 0; i < 32; i += 8)
      dst[(size_t)(bx + ty + i) * n + by + tx] = f2bf(tile[tx][ty + i]);
  } else {
    const int bid = (blockIdx.z - 4) * 1024 + blockIdx.y * 32 + blockIdx.x;
    const int t = threadIdx.y * 32 + threadIdx.x;
    const int i = (bid * 256 + t) * 4;
    float4 f = *(const float4*)(X + i);
    ushort4 o = make_ushort4(f2bf(f.x), f2bf(f.y), f2bf(f.z), f2bf(f.w));
    *(ushort4*)(Xb + i) = o;
  }
}

// ------------------------------ GEMM (B^T) ---------------------------------
// C[m][n] = alpha * sum_k A[m][k] * Bt[n][k]
// 128x128 block tile, BK=64, 16x16x32 bf16 MFMA, LDS xor-swizzle (R1).
// NW=4: 256 thr, 4 waves of 64x64. NW=8: 512 thr, 8 waves of 32x64.
// tri : blockIdx.x is a lower-triangular tile index.
// kcap: K_eff = min(K, m0+128) (causal PV truncation) + heavy-rows-first.
// gx>0: 1D grid, XCD-aware decode (8-row groups, bx-major, yy fastest).
template <typename OutT, int NW>
__global__ __launch_bounds__(NW * 64, NW / 2)
void gemm_bt(const unsigned short* __restrict__ A, int lda, long long sA,
             const unsigned short* __restrict__ B, int ldb, long long sB,
             OutT* __restrict__ Cp, int ldc, long long sC,
             int K, float alpha, int tri, int kcap, int gx) {
  A  += (long long)blockIdx.z * sA;
  B  += (long long)blockIdx.z * sB;
  Cp += (long long)blockIdx.z * sC;

  int by, bx;
  if (tri) {
    const int idx = blockIdx.x;
    by = (int)((sqrtf(8.f * idx + 1.f) - 1.f) * 0.5f);
    while (by * (by + 1) / 2 > idx) --by;
    while ((by + 1) * (by + 2) / 2 <= idx) ++by;
    bx = idx - by * (by + 1) / 2;
  } else if (gx > 0) {
    const int id = blockIdx.x;
    const int gs = gx * 8;
    const int g = id / gs, r = id - g * gs;
    bx = r >> 3;
    by = g * 8 + (r & 7);
    if (kcap) by = (gridDim.x / gx) - 1 - by;  // heavy rows first
  } else {
    by = blockIdx.y;
    bx = blockIdx.x;
  }
  const int m0 = by * 128;
  const int n0 = bx * 128;
  const int Keff = kcap ? min(K, m0 + 128) : K;

  const int tid  = threadIdx.x;
  const int lane = tid & 63;
  const int w    = tid >> 6;
  const int wm   = (NW == 4) ? (w >> 1) * 64 : (w >> 1) * 32;
  const int wn   = (w & 1) * 64;
  const int quad = lane >> 4;
  const int l16  = lane & 15;
  constexpr int AI = (NW == 4) ? 4 : 2;   // A-fragment count per wave
  constexpr int NR = 128 / (NW * 8);      // staging rounds per tile

  __shared__ unsigned short As[8192];
  __shared__ unsigned short Bs[8192];

  f32x4 acc[AI][4];
#pragma unroll
  for (int i = 0; i < AI; ++i)
#pragma unroll
    for (int j = 0; j < 4; ++j)
      acc[i][j] = (f32x4){0.f, 0.f, 0.f, 0.f};

  const int srow = tid >> 3;
  const int scol = ((tid & 7) ^ (srow & 7)) * 8;
  const unsigned short* gA = A + (long long)(m0 + srow) * lda + scol;
  const unsigned short* gB = B + (long long)(n0 + srow) * ldb + scol;
  const int rsw = l16 & 7;

  for (int kt = 0; kt < Keff; kt += 64) {
    __syncthreads();
#pragma unroll
    for (int r = 0; r < NR; ++r) {
      GLDS(gA + (long long)(r * NW * 8) * lda + kt, As + r * NW * 512 + tid * 8);
      GLDS(gB + (long long)(r * NW * 8) * ldb + kt, Bs + r * NW * 512 + tid * 8);
    }
    __syncthreads();
#pragma unroll
    for (int ks = 0; ks < 2; ++ks) {
      bf16x8 af[AI], bfr[4];
#pragma unroll
      for (int i = 0; i < AI; ++i)
        af[i] = *(const bf16x8*)(As + (wm + i * 16 + l16) * 64 +
                                 ((ks * 4 + quad) ^ rsw) * 8);
#pragma unroll
      for (int j = 0; j < 4; ++j)
        bfr[j] = *(const bf16x8*)(Bs + (wn + j * 16 + l16) * 64 +
                                  ((ks * 4 + quad) ^ rsw) * 8);
#pragma unroll
      for (int i = 0; i < AI; ++i)
#pragma unroll
        for (int j = 0; j < 4; ++j)
          acc[i][j] = __builtin_amdgcn_mfma_f32_16x16x32_bf16(af[i], bfr[j],
                                                              acc[i][j], 0, 0, 0);
    }
  }

  // C/D layout (m89/m91 verified): col = lane&15, row = quad*4 + reg
#pragma unroll
  for (int i = 0; i < AI; ++i) {
#pragma unroll
    for (int j = 0; j < 4; ++j) {
      const int row = m0 + wm + i * 16 + quad * 4;
      const int col = n0 + wn + j * 16 + l16;
#pragma unroll
      for (int r = 0; r < 4; ++r) {
        float v = acc[i][j][r] * alpha;
        if constexpr (sizeof(OutT) == 2)
          Cp[(long long)(row + r) * ldc + col] = (OutT)f2bf(v);
        else
          Cp[(long long)(row + r) * ldc + col] = v;
      }
    }
  }
}

// ----------------------- QKV GEMM (128x128, 4 waves) -----------------------
// N=3072 fused; XCD swizzle via gx. Epilogue: Q | K (+8M) | V^T (+16M,
// Vt[b][c][t]). With Wcat slot 2 = WvoT, "V" is X@Wv@Wo.
__global__ __launch_bounds__(256, 2)
void gemm_qkv(const unsigned short* __restrict__ A, int lda,
              const unsigned short* __restrict__ B, int ldb,
              unsigned short* __restrict__ Cp, int K, int gx) {
  const int id = blockIdx.x;
  const int gs = gx * 8;
  const int g = id / gs, r = id - g * gs;
  const int bx = r >> 3;
  const int by = g * 8 + (r & 7);
  const int m0 = by * 128;
  const int n0 = bx * 128;

  const int tid  = threadIdx.x;
  const int lane = tid & 63;
  const int w    = tid >> 6;
  const int wm   = (w >> 1) * 64;
  const int wn   = (w & 1) * 64;
  const int quad = lane >> 4;
  const int l16  = lane & 15;

  __shared__ unsigned short As[8192];
  __shared__ unsigned short Bs[8192];

  f32x4 acc[4][4];
#pragma unroll
  for (int i = 0; i < 4; ++i)
#pragma unroll
    for (int j = 0; j < 4; ++j)
      acc[i][j] = (f32x4){0.f, 0.f, 0.f, 0.f};

  const int srow = tid >> 3;
  const int scol = ((tid & 7) ^ (srow & 7)) * 8;
  const unsigned short* gA = A + (long long)(m0 + srow) * lda + scol;
  const unsigned short* gB = B + (long long)(n0 + srow) * ldb + scol;
  const int rsw = l16 & 7;

  for (int kt = 0; kt < K; kt += 64) {
    __syncthreads();
#pragma unroll
    for (int r2 = 0; r2 < 4; ++r2) {
      GLDS(gA + (long long)(r2 * 32) * lda + kt, As + r2 * 2048 + tid * 8);
      GLDS(gB + (long long)(r2 * 32) * ldb + kt, Bs + r2 * 2048 + tid * 8);
    }
    __syncthreads();
#pragma unroll
    for (int ks = 0; ks < 2; ++ks) {
      bf16x8 af[4], bfr[4];
#pragma unroll
      for (int i = 0; i < 4; ++i)
        af[i] = *(const bf16x8*)(As + (wm + i * 16 + l16) * 64 +
                                 ((ks * 4 + quad) ^ rsw) * 8);
#pragma unroll
      for (int j = 0; j < 4; ++j)
        bfr[j] = *(const bf16x8*)(Bs + (wn + j * 16 + l16) * 64 +
                                  ((ks * 4 + quad) ^ rsw) * 8);
#pragma unroll
      for (int i = 0; i < 4; ++i)
#pragma unroll
        for (int j = 0; j < 4; ++j)
          acc[i][j] = __builtin_amdgcn_mfma_f32_16x16x32_bf16(af[i], bfr[j],
                                                              acc[i][j], 0, 0, 0);
    }
  }

#pragma unroll
  for (int i = 0; i < 4; ++i) {
#pragma unroll
    for (int j = 0; j < 4; ++j) {
      const int row = m0 + wm + i * 16 + quad * 4;
      const int col = n0 + wn + j * 16 + l16;
      if (col >= 2048) {  // V(=X@Wv@Wo), stored transposed: Vt[b][c][t]
        const int b = row >> 11, t = row & 2047, cv = col - 2048;
        ushort4 o = make_ushort4(f2bf(acc[i][j][0]), f2bf(acc[i][j][1]),
                                 f2bf(acc[i][j][2]), f2bf(acc[i][j][3]));
        *(ushort4*)(Cp + 16777216LL + ((long long)(b * 1024 + cv)) * 2048 + t) = o;
      } else {  // Q (col<1024) or K (col in [1024,2048))
        unsigned short* dst = Cp + (col >= 1024 ? 8388608LL - 1024 : 0);
#pragma unroll
        for (int r2 = 0; r2 < 4; ++r2)
          dst[(long long)(row + r2) * 1024 + col] = f2bf(acc[i][j][r2]);
      }
    }
  }
}

// ------------------------- causal softmax (in place) -----------------------
// 128-granular limit (matches PV's Keff = m0+128 read window).
__global__ __launch_bounds__(256)
void softmax_causal(unsigned short* __restrict__ S, int T) {
  const long long row = blockIdx.x;
  const int t = (int)(row & (long long)(T - 1));
  const int limit = ((t >> 7) + 1) << 7;
  unsigned short* p = S + row * T;
  const int tid  = threadIdx.x;
  const int base = tid * 8;
  const bool active = base < limit;

  short8 raw = {};
  if (active) raw = *(const short8*)(p + base);
  float x[8];
  float mx = -1e30f;
#pragma unroll
  for (int j = 0; j < 8; ++j) {
    bool valid = active && (base + j) <= t;
    x[j] = valid ? bf2f((unsigned short)raw[j]) : -1e30f;
    mx = fmaxf(mx, x[j]);
  }
#pragma unroll
  for (int off = 32; off > 0; off >>= 1) mx = fmaxf(mx, __shfl_xor(mx, off));
  __shared__ float red[8];
  const int wv = tid >> 6;
  if ((tid & 63) == 0) red[wv] = mx;
  __syncthreads();
  mx = fmaxf(fmaxf(red[0], red[1]), fmaxf(red[2], red[3]));

  float sum = 0.f;
#pragma unroll
  for (int j = 0; j < 8; ++j) {
    bool valid = active && (base + j) <= t;
    x[j] = valid ? __expf(x[j] - mx) : 0.f;
    sum += x[j];
  }
#pragma unroll
  for (int off = 32; off > 0; off >>= 1) sum += __shfl_xor(sum, off);
  if ((tid & 63) == 0) red[4 + wv] = sum;
  __syncthreads();
  sum = red[4] + red[5] + red[6] + red[7];
  const float inv = 1.f / sum;

  if (active) {
    unsigned short out[8];
#pragma unroll
    for (int j = 0; j < 8; ++j) out[j] = f2bf(x[j] * inv);
    *(short8*)(p + base) = *(const short8*)out;
  }
}

// ---------------------------------------------------------------------------
extern "C" void kernel_launch(void* const* d_in, const int* in_sizes, int n_in,
                              void* d_out, int out_size, void* d_ws,
                              size_t ws_size, hipStream_t stream) {
  (void)in_sizes; (void)n_in; (void)out_size; (void)ws_size;
  const int Bb = 4, T = 2048, C = 1024;
  const int M = Bb * T;  // 8192

  const float* X  = (const float*)d_in[0];
  const float* Wq = (const float*)d_in[1];
  const float* Wk = (const float*)d_in[2];
  const float* Wv = (const float*)d_in[3];
  const float* Wo = (const float*)d_in[4];
  float* Out = (float*)d_out;

  // ws carve: 70MB (proven budget is >=72). Q/Kb/Vt contiguous triple.
  char* w = (char*)d_ws;
  unsigned short* Wcat = (unsigned short*)w; w += (size_t)3 * C * C * 2;  // 6MB
  unsigned short* Q    = (unsigned short*)w; w += (size_t)M * C * 2;      // 16MB
  unsigned short* Kb   = (unsigned short*)w; w += (size_t)M * C * 2;      // 16MB (Q+8M)
  unsigned short* Vt   = (unsigned short*)w; w += (size_t)M * C * 2;      // 16MB (Q+16M)
  unsigned short* Xb   = (unsigned short*)w; w += (size_t)M * C * 2;      // 16MB
  // d_out (32MB) phases: [Wvb 2MB | Wot 2MB] -> S (bf16 32MB) -> final fp32
  unsigned short* Wvb  = (unsigned short*)d_out;               // Wv, cast only
  unsigned short* Wot  = (unsigned short*)d_out + (size_t)C * C;  // Wo^T
  unsigned short* S    = (unsigned short*)d_out;               // overwrites both
  float*          OutT = (float*)Q;  // 32MB over dead Q+Kb (PV output)

  // prep: Wq->Wcat0, Wk->Wcat1 (T), Wv->Wvb (cast), Wo->Wot (T), X->Xb
  prep<<<dim3(32, 32, 12), dim3(32, 8), 0, stream>>>(X, Wq, Wk, Wv, Wo, Xb,
                                                     Wcat, Wvb, Wot, C);

  // WvoT[n][k] = sum_i Wot[n][i]*Wvb[k][i] = (Wv@Wo)^T[n][k] -> Wcat slot 2
  gemm_bt<unsigned short, 4><<<dim3(C / 128, C / 128, 1), dim3(256), 0, stream>>>(
      Wot, C, 0, Wvb, C, 0, Wcat + (size_t)2 * C * C, C, 0, C, 1.f, 0, 0, 0);

  // fused QKV: [8192 x 3072] = Xb @ Wcat^T-layout (V-slot = Wv@Wo)
  gemm_qkv<<<dim3((3 * C / 128) * (M / 128)), dim3(256), 0, stream>>>(
      Xb, C, Wcat, C, Q, C, /*gx=*/3 * C / 128);

  // S[b] = Q[b] @ K[b]^T / 32 — lower-tri 128-tiles (136 x 4), into d_out
  const int ntri = (T / 128) * (T / 128 + 1) / 2;
  gemm_bt<unsigned short, 8><<<dim3(ntri, 1, Bb), dim3(512), 0, stream>>>(
      Q, C, (long long)T * C, Kb, C, (long long)T * C,
      S, T, (long long)T * T, C, 0.03125f, 1, 0, 0);

  // causal softmax (128-granular row truncation)
  softmax_causal<<<M, 256, 0, stream>>>(S, T);

  // FINAL GEMM: OutT[b] = P[b] @ (V@Wo)[b]  (fp32, into ws over dead Q+Kb)
  gemm_bt<float, 8><<<dim3((C / 128) * (T / 128), 1, Bb), dim3(512), 0, stream>>>(
      S, T, (long long)T * T, Vt, T, (long long)C * T,
      OutT, C, (long long)T * C, T, 1.f, 0, 1, /*gx=*/C / 128);

  // move result into d_out (S is dead once PV finishes; stream-ordered)
  hipMemcpyAsync(Out, OutT, (size_t)M * C * sizeof(float),
                 hipMemcpyDeviceToDevice, stream);
}